// Round 2
// baseline (117.446 us; speedup 1.0000x reference)
//
#include <hip/hip_runtime.h>
#include <hip/hip_bf16.h>

typedef __attribute__((ext_vector_type(4))) float f32x4;
typedef __attribute__((ext_vector_type(2))) int   i32x2;
typedef __attribute__((ext_vector_type(4))) int   i32x4;
typedef __attribute__((ext_vector_type(8))) short short8;

#define GLDS16(gsrc, ldst) __builtin_amdgcn_global_load_lds(                 \
    (const __attribute__((address_space(1))) void*)(gsrc),                   \
    (__attribute__((address_space(3))) void*)(ldst), 16, 0, 0)

__device__ __forceinline__ unsigned short f2bf(float x) {
  __hip_bfloat16 h = __float2bfloat16(x);
  union { __hip_bfloat16 h1; unsigned short u; } c; c.h1 = h; return c.u;
}
__device__ __forceinline__ unsigned pk2(float a, float b) {
  __hip_bfloat162 h = __float22bfloat162_rn(make_float2(a, b));
  union { __hip_bfloat162 h2; unsigned u; } c; c.h2 = h; return c.u;
}

// ---------------------------------------------------------------------------
// Prep: W1u = edge_w[:256]@G1, W1v = edge_w[256:]@G1 (f32),
//       c1 = edge_b@G1 + gb0, W2T/W3T = bf16 transposes of gw1/gw2.
// grid 513 x 256
// ---------------------------------------------------------------------------
__global__ void k_prep(const float* __restrict__ edge_w, const float* __restrict__ edge_b,
                       const float* __restrict__ gw0, const float* __restrict__ gb0,
                       const float* __restrict__ gw1, const float* __restrict__ gw2,
                       float* __restrict__ W1u, float* __restrict__ W1v,
                       float* __restrict__ c1,
                       unsigned short* __restrict__ W2T, unsigned short* __restrict__ W3T) {
  const int blk = blockIdx.x, t = threadIdx.x;
  __shared__ float eu[256], ev[256];
  if (blk < 256) {
    eu[t] = edge_w[blk * 256 + t];
    ev[t] = edge_w[(256 + blk) * 256 + t];
    __syncthreads();
    float su = 0.f, sv = 0.f;
    for (int o = 0; o < 256; ++o) {
      float g = gw0[o * 256 + t];
      su += eu[o] * g; sv += ev[o] * g;
    }
    W1u[blk * 256 + t] = su;
    W1v[blk * 256 + t] = sv;
  } else if (blk < 512) {
    int m = blk - 256;                       // output-feature index
    W2T[m * 256 + t] = f2bf(gw1[t * 256 + m]);
    W3T[m * 256 + t] = f2bf(gw2[t * 256 + m]);
  } else {
    float s = gb0[t];
    for (int o = 0; o < 256; ++o) s += edge_b[o] * gw0[o * 256 + t];
    c1[t] = s;
  }
}

// ---------------------------------------------------------------------------
// U1 = x @ W1u, V1 = x @ W1v  (f32).  grid 256 x 256, 8 rows/block.
// ---------------------------------------------------------------------------
__global__ void k_uv(const float* __restrict__ x,
                     const float* __restrict__ W1u, const float* __restrict__ W1v,
                     float* __restrict__ U1, float* __restrict__ V1) {
  const int blk = blockIdx.x, t = threadIdx.x;
  const int r0 = blk * 8;
  __shared__ float xs[8][256];
  for (int s = 0; s < 8; ++s) xs[s][t] = x[(r0 + s) * 256 + t];
  __syncthreads();
  float au[8], av[8];
#pragma unroll
  for (int r = 0; r < 8; ++r) { au[r] = 0.f; av[r] = 0.f; }
  for (int k = 0; k < 256; ++k) {
    float wu = W1u[k * 256 + t];
    float wv = W1v[k * 256 + t];
#pragma unroll
    for (int r = 0; r < 8; ++r) {
      float xv = xs[r][k];
      au[r] += xv * wu; av[r] += xv * wv;
    }
  }
  for (int r = 0; r < 8; ++r) {
    U1[(r0 + r) * 256 + t] = au[r];
    V1[(r0 + r) * 256 + t] = av[r];
  }
}

// ---------------------------------------------------------------------------
// Main fused kernel: per block = (batch b, i = itile): 64 pair-rows (j=0..63).
//   h1 = relu(U1[b,j] + V1[b,i] + c1)        -> LDS bf16 [64][64] per K-chunk
//   h2 = relu(h1 @ G2 + b2)   (swapped MFMA: acc = G2^T tile * h1^T)
//   h3 = relu(h2 @ G3 + b3)   (swapped), then sum over the 64 rows
// partials[blk][256] = per-block pair-sum.
// 256 threads (4 waves), wave m-tile 64 (features), n-tile 64 (rows).
// ---------------------------------------------------------------------------
__launch_bounds__(256, 2)
__global__ void k_main(const float* __restrict__ U1, const float* __restrict__ V1,
                       const float* __restrict__ c1,
                       const unsigned short* __restrict__ W2T,
                       const unsigned short* __restrict__ W3T,
                       const float* __restrict__ b2, const float* __restrict__ b3,
                       float* __restrict__ partials) {
  __shared__ unsigned short h1s[64 * 64];    // [row][k] bf16, row stride 64, XOR-swizzled 16B slots
  __shared__ unsigned short wts[256 * 64];   // [feat][k] bf16 W-tile, XOR-swizzled
  __shared__ unsigned short h2s[64 * 256];   // [row][c2] bf16, XOR-swizzled
  __shared__ float vcs[256];
  __shared__ float b2s[256], b3s[256];
  __shared__ float xgs[256];

  const int t = threadIdx.x;
  const int blk = blockIdx.x;
  const int b = blk >> 6;
  const int itile = blk & 63;
  const int wid = t >> 6, lane = t & 63;
  const int g = lane >> 4, q = lane & 15;
  const int mo = wid * 64;                   // wave's feature-range base

  // stage vc = V1[b][itile] + c1, biases
  vcs[t] = V1[(size_t)(b * 64 + itile) * 256 + t] + c1[t];
  b2s[t] = b2[t];
  b3s[t] = b3[t];
  __syncthreads();

  const float* Ubase = U1 + (size_t)(b * 64) * 256;

  f32x4 acc[4][4];
#pragma unroll
  for (int mf = 0; mf < 4; ++mf)
#pragma unroll
    for (int nf = 0; nf < 4; ++nf) acc[mf][nf] = (f32x4){0.f, 0.f, 0.f, 0.f};

  // ---------------- GEMM1: acc = G2^T * h1^T  (K = 256, chunks of 64) -------
  for (int ch = 0; ch < 4; ++ch) {
    // stage W2T tile [256][64] via global_load_lds, source pre-swizzled
#pragma unroll
    for (int rr = 0; rr < 8; ++rr) {
      int s = (rr * 4 + wid) * 64 + lane;    // 16B-slot index 0..2047
      int m = s >> 3, sl = s & 7;
      const unsigned short* src = W2T + m * 256 + ch * 64 + ((sl ^ (m & 7)) * 8);
      GLDS16(src, wts + (rr * 4 + wid) * 512);
    }
    // stage h1 tile (compute from U1 + vc)
#pragma unroll
    for (int hh = 0; hh < 2; ++hh) {
      int s = t * 2 + hh;
      int row = s >> 3, sl = s & 7;
      int k0 = ch * 64 + sl * 8;
      const float* up = Ubase + row * 256 + k0;
      f32x4 u0 = *(const f32x4*)up;
      f32x4 u1 = *(const f32x4*)(up + 4);
      f32x4 v0 = *(const f32x4*)(vcs + k0);
      f32x4 v1 = *(const f32x4*)(vcs + k0 + 4);
      float r0 = fmaxf(u0.x + v0.x, 0.f), r1 = fmaxf(u0.y + v0.y, 0.f);
      float r2 = fmaxf(u0.z + v0.z, 0.f), r3 = fmaxf(u0.w + v0.w, 0.f);
      float r4 = fmaxf(u1.x + v1.x, 0.f), r5 = fmaxf(u1.y + v1.y, 0.f);
      float r6 = fmaxf(u1.z + v1.z, 0.f), r7 = fmaxf(u1.w + v1.w, 0.f);
      i32x4 wv = { (int)pk2(r0, r1), (int)pk2(r2, r3), (int)pk2(r4, r5), (int)pk2(r6, r7) };
      *(i32x4*)(h1s + row * 64 + ((sl ^ (row & 7)) * 8)) = wv;
    }
    __syncthreads();
#pragma unroll
    for (int kc = 0; kc < 2; ++kc) {
      short8 a[4], bf[4];
#pragma unroll
      for (int mf = 0; mf < 4; ++mf) {
        int m = mo + 16 * mf + q;
        a[mf] = *(const short8*)(wts + m * 64 + (((kc * 4 + g) ^ (m & 7)) * 8));
      }
#pragma unroll
      for (int nf = 0; nf < 4; ++nf) {
        int row = q + 16 * nf;
        bf[nf] = *(const short8*)(h1s + row * 64 + (((kc * 4 + g) ^ (row & 7)) * 8));
      }
#pragma unroll
      for (int mf = 0; mf < 4; ++mf)
#pragma unroll
        for (int nf = 0; nf < 4; ++nf)
          acc[mf][nf] = __builtin_amdgcn_mfma_f32_16x16x32_bf16(a[mf], bf[nf], acc[mf][nf], 0, 0, 0);
    }
    __syncthreads();
  }

  // h2 = relu(acc + b2) -> LDS bf16 [64][256], packed b64 writes
#pragma unroll
  for (int mf = 0; mf < 4; ++mf) {
    int c2b = mo + 16 * mf + 4 * g;          // lane's 4 consecutive features
    f32x4 bb = *(const f32x4*)(b2s + c2b);
#pragma unroll
    for (int nf = 0; nf < 4; ++nf) {
      int row = q + 16 * nf;
      f32x4 v = acc[mf][nf];
      float e0 = fmaxf(v.x + bb.x, 0.f), e1 = fmaxf(v.y + bb.y, 0.f);
      float e2 = fmaxf(v.z + bb.z, 0.f), e3 = fmaxf(v.w + bb.w, 0.f);
      i32x2 wv = { (int)pk2(e0, e1), (int)pk2(e2, e3) };
      *(i32x2*)(h2s + row * 256 + (((c2b >> 3) ^ (row & 7)) * 8) + (c2b & 7)) = wv;
    }
  }
  __syncthreads();

  // ---------------- GEMM2: acc2 = G3^T * h2^T ------------------------------
  f32x4 acc2[4][4];
#pragma unroll
  for (int mf = 0; mf < 4; ++mf)
#pragma unroll
    for (int nf = 0; nf < 4; ++nf) acc2[mf][nf] = (f32x4){0.f, 0.f, 0.f, 0.f};

  for (int ch = 0; ch < 4; ++ch) {
#pragma unroll
    for (int rr = 0; rr < 8; ++rr) {
      int s = (rr * 4 + wid) * 64 + lane;
      int m = s >> 3, sl = s & 7;
      const unsigned short* src = W3T + m * 256 + ch * 64 + ((sl ^ (m & 7)) * 8);
      GLDS16(src, wts + (rr * 4 + wid) * 512);
    }
    __syncthreads();
#pragma unroll
    for (int kc = 0; kc < 2; ++kc) {
      short8 a[4], bf[4];
#pragma unroll
      for (int mf = 0; mf < 4; ++mf) {
        int m = mo + 16 * mf + q;
        a[mf] = *(const short8*)(wts + m * 64 + (((kc * 4 + g) ^ (m & 7)) * 8));
      }
#pragma unroll
      for (int nf = 0; nf < 4; ++nf) {
        int row = q + 16 * nf;
        int slot = ch * 8 + kc * 4 + g;
        bf[nf] = *(const short8*)(h2s + row * 256 + ((slot ^ (row & 7)) * 8));
      }
#pragma unroll
      for (int mf = 0; mf < 4; ++mf)
#pragma unroll
        for (int nf = 0; nf < 4; ++nf)
          acc2[mf][nf] = __builtin_amdgcn_mfma_f32_16x16x32_bf16(a[mf], bf[nf], acc2[mf][nf], 0, 0, 0);
    }
    __syncthreads();
  }

  // h3 = relu(acc2 + b3); pair-sum over rows: in-frag + 16-lane butterfly
#pragma unroll
  for (int mf = 0; mf < 4; ++mf) {
    int n3b = mo + 16 * mf + 4 * g;
    f32x4 bb = *(const f32x4*)(b3s + n3b);
    f32x4 sum = (f32x4){0.f, 0.f, 0.f, 0.f};
#pragma unroll
    for (int nf = 0; nf < 4; ++nf) {
      f32x4 v = acc2[mf][nf];
      sum.x += fmaxf(v.x + bb.x, 0.f);
      sum.y += fmaxf(v.y + bb.y, 0.f);
      sum.z += fmaxf(v.z + bb.z, 0.f);
      sum.w += fmaxf(v.w + bb.w, 0.f);
    }
#pragma unroll
    for (int msk = 1; msk < 16; msk <<= 1) {
      sum.x += __shfl_xor(sum.x, msk);
      sum.y += __shfl_xor(sum.y, msk);
      sum.z += __shfl_xor(sum.z, msk);
      sum.w += __shfl_xor(sum.w, msk);
    }
    if (q == 0) *(f32x4*)(xgs + n3b) = sum;
  }
  __syncthreads();
  partials[(size_t)blk * 256 + t] = xgs[t];
}

// ---------------------------------------------------------------------------
// Reduce partials per batch + f-MLP (f32). grid 32 x 256.
// ---------------------------------------------------------------------------
__global__ void k_fmlp(const float* __restrict__ partials,
                       const float* __restrict__ f1w, const float* __restrict__ f1b,
                       const float* __restrict__ f2w, const float* __restrict__ f2b,
                       const float* __restrict__ f3w, const float* __restrict__ f3b,
                       float* __restrict__ out) {
  const int b = blockIdx.x, t = threadIdx.x;
  __shared__ float xg[256], x1[256], x2[256];
  float s = 0.f;
  for (int k = 0; k < 64; ++k) s += partials[(size_t)(b * 64 + k) * 256 + t];
  xg[t] = s;
  __syncthreads();
  float a1 = f1b[t];
  for (int k = 0; k < 256; ++k) a1 += xg[k] * f1w[k * 256 + t];
  x1[t] = fmaxf(a1, 0.f);
  __syncthreads();
  float a2 = f2b[t];
  for (int k = 0; k < 256; ++k) a2 += x1[k] * f2w[k * 256 + t];
  x2[t] = fmaxf(a2, 0.f);
  __syncthreads();
  if (t < 128) {
    float a3 = f3b[t];
    for (int k = 0; k < 256; ++k) a3 += x2[k] * f3w[k * 128 + t];
    out[b * 128 + t] = a3;
  }
}

// Fallback: zero d_out if workspace is too small (diagnostic, avoids fault).
__global__ void k_zero(float* __restrict__ out, int n) {
  int i = blockIdx.x * 256 + threadIdx.x;
  if (i < n) out[i] = 0.f;
}

// ---------------------------------------------------------------------------
extern "C" void kernel_launch(void* const* d_in, const int* in_sizes, int n_in,
                              void* d_out, int out_size, void* d_ws, size_t ws_size,
                              hipStream_t stream) {
  const float* x      = (const float*)d_in[0];
  const float* edge_w = (const float*)d_in[1];
  const float* edge_b = (const float*)d_in[2];
  const float *gw0, *gw1, *gw2, *gb0, *gb1, *gb2;
  const float *f1w, *f1b, *f2w, *f2b, *f3w, *f3b;

  if (n_in >= 15 && in_sizes[3] == 65536 && in_sizes[4] == 65536 && in_sizes[5] == 65536) {
    // 15 inputs, grouped lists: gw0,gw1,gw2,gb0,gb1,gb2
    gw0 = (const float*)d_in[3]; gw1 = (const float*)d_in[4]; gw2 = (const float*)d_in[5];
    gb0 = (const float*)d_in[6]; gb1 = (const float*)d_in[7]; gb2 = (const float*)d_in[8];
    f1w = (const float*)d_in[9];  f1b = (const float*)d_in[10];
    f2w = (const float*)d_in[11]; f2b = (const float*)d_in[12];
    f3w = (const float*)d_in[13]; f3b = (const float*)d_in[14];
  } else if (n_in >= 15 && in_sizes[3] == 65536 && in_sizes[4] == 256) {
    // 15 inputs, interleaved: gw0,gb0,gw1,gb1,gw2,gb2
    gw0 = (const float*)d_in[3]; gb0 = (const float*)d_in[4];
    gw1 = (const float*)d_in[5]; gb1 = (const float*)d_in[6];
    gw2 = (const float*)d_in[7]; gb2 = (const float*)d_in[8];
    f1w = (const float*)d_in[9];  f1b = (const float*)d_in[10];
    f2w = (const float*)d_in[11]; f2b = (const float*)d_in[12];
    f3w = (const float*)d_in[13]; f3b = (const float*)d_in[14];
  } else {
    // 11 inputs, stacked lists: g_ws = [3,256,256] in d_in[3], g_bs = [3,256] in d_in[4]
    const float* gws = (const float*)d_in[3];
    const float* gbs = (const float*)d_in[4];
    gw0 = gws;          gw1 = gws + 65536;  gw2 = gws + 131072;
    gb0 = gbs;          gb1 = gbs + 256;    gb2 = gbs + 512;
    f1w = (const float*)d_in[5];  f1b = (const float*)d_in[6];
    f2w = (const float*)d_in[7];  f2b = (const float*)d_in[8];
    f3w = (const float*)d_in[9];  f3b = (const float*)d_in[10];
  }

  char* ws = (char*)d_ws;
  float*          W1u      = (float*)(ws);                    // 256x256 f32
  float*          W1v      = (float*)(ws + 262144);           // 256x256 f32
  float*          c1       = (float*)(ws + 524288);           // 256 f32
  unsigned short* W2T      = (unsigned short*)(ws + 525568);  // 256x256 bf16
  unsigned short* W3T      = (unsigned short*)(ws + 656640);  // 256x256 bf16
  float*          U1       = (float*)(ws + 787712);           // 2048x256 f32
  float*          V1       = (float*)(ws + 2884864);          // 2048x256 f32
  float*          partials = (float*)(ws + 4982016);          // 2048x256 f32
  const size_t need = 7079168;
  (void)out_size; (void)n_in;

  if (ws_size < need) {
    // Workspace too small for this layout: emit a clean (wrong) zero output
    // instead of faulting, so the failure mode is diagnosable.
    k_zero<<<dim3((out_size + 255) / 256), dim3(256), 0, stream>>>((float*)d_out, out_size);
    return;
  }

  k_prep<<<dim3(513), dim3(256), 0, stream>>>(edge_w, edge_b, gw0, gb0, gw1, gw2,
                                              W1u, W1v, c1, W2T, W3T);
  k_uv<<<dim3(256), dim3(256), 0, stream>>>(x, W1u, W1v, U1, V1);
  k_main<<<dim3(2048), dim3(256), 0, stream>>>(U1, V1, c1, W2T, W3T, gb1, gb2, partials);
  k_fmlp<<<dim3(32), dim3(256), 0, stream>>>(partials, f1w, f1b, f2w, f2b, f3w, f3b,
                                             (float*)d_out);
}

// Round 3
// 100.849 us; speedup vs baseline: 1.1646x; 1.1646x over previous
//
#include <hip/hip_runtime.h>
#include <hip/hip_bf16.h>

typedef __attribute__((ext_vector_type(4))) float f32x4;
typedef __attribute__((ext_vector_type(2))) int   i32x2;
typedef __attribute__((ext_vector_type(4))) int   i32x4;
typedef __attribute__((ext_vector_type(8))) short short8;

#define GLDS16(gsrc, ldst) __builtin_amdgcn_global_load_lds(                 \
    (const __attribute__((address_space(1))) void*)(gsrc),                   \
    (__attribute__((address_space(3))) void*)(ldst), 16, 0, 0)

__device__ __forceinline__ unsigned short f2bf(float x) {
  __hip_bfloat16 h = __float2bfloat16(x);
  union { __hip_bfloat16 h1; unsigned short u; } c; c.h1 = h; return c.u;
}
__device__ __forceinline__ unsigned pk2(float a, float b) {
  __hip_bfloat162 h = __float22bfloat162_rn(make_float2(a, b));
  union { __hip_bfloat162 h2; unsigned u; } c; c.h2 = h; return c.u;
}
__device__ __forceinline__ float bf2f(unsigned short u) {
  union { unsigned u32; float f; } c; c.u32 = ((unsigned)u) << 16; return c.f;
}

// ---------------------------------------------------------------------------
// Prep (unchanged): W1u = edge_w[:256]@G1, W1v = edge_w[256:]@G1 (f32),
// c1 = edge_b@G1 + gb0, W2T/W3T = bf16 transposes of gw1/gw2. grid 513 x 256
// ---------------------------------------------------------------------------
__global__ void k_prep(const float* __restrict__ edge_w, const float* __restrict__ edge_b,
                       const float* __restrict__ gw0, const float* __restrict__ gb0,
                       const float* __restrict__ gw1, const float* __restrict__ gw2,
                       float* __restrict__ W1u, float* __restrict__ W1v,
                       float* __restrict__ c1,
                       unsigned short* __restrict__ W2T, unsigned short* __restrict__ W3T) {
  const int blk = blockIdx.x, t = threadIdx.x;
  __shared__ float eu[256], ev[256];
  if (blk < 256) {
    eu[t] = edge_w[blk * 256 + t];
    ev[t] = edge_w[(256 + blk) * 256 + t];
    __syncthreads();
    float su = 0.f, sv = 0.f;
    for (int o = 0; o < 256; ++o) {
      float gg = gw0[o * 256 + t];
      su += eu[o] * gg; sv += ev[o] * gg;
    }
    W1u[blk * 256 + t] = su;
    W1v[blk * 256 + t] = sv;
  } else if (blk < 512) {
    int m = blk - 256;
    W2T[m * 256 + t] = f2bf(gw1[t * 256 + m]);
    W3T[m * 256 + t] = f2bf(gw2[t * 256 + m]);
  } else {
    float s = gb0[t];
    for (int o = 0; o < 256; ++o) s += edge_b[o] * gw0[o * 256 + t];
    c1[t] = s;
  }
}

// ---------------------------------------------------------------------------
// U1(bf16) = x @ W1u, V1(f32) = x @ W1v. grid 256 x 512: waves 0-3 -> U, 4-7 -> V.
// ---------------------------------------------------------------------------
__global__ void k_uv(const float* __restrict__ x,
                     const float* __restrict__ W1u, const float* __restrict__ W1v,
                     unsigned short* __restrict__ U1, float* __restrict__ V1) {
  const int blk = blockIdx.x, t = threadIdx.x;
  const int r0 = blk * 8;
  __shared__ float xs[2048];
  *(f32x4*)(xs + t * 4) = *(const f32x4*)(x + (size_t)r0 * 256 + t * 4);
  __syncthreads();
  const int sel = t >> 8, col = t & 255;
  const float* W = sel ? W1v : W1u;
  float a[8];
#pragma unroll
  for (int r = 0; r < 8; ++r) a[r] = 0.f;
  for (int k = 0; k < 256; ++k) {
    float w = W[k * 256 + col];
#pragma unroll
    for (int r = 0; r < 8; ++r) a[r] += xs[r * 256 + k] * w;
  }
  if (sel == 0) {
#pragma unroll
    for (int r = 0; r < 8; ++r) U1[(size_t)(r0 + r) * 256 + col] = f2bf(a[r]);
  } else {
#pragma unroll
    for (int r = 0; r < 8; ++r) V1[(size_t)(r0 + r) * 256 + col] = a[r];
  }
}

// ---------------------------------------------------------------------------
// Main fused kernel. Per block (b, itile): 64 pair-rows.
// K-chunks of 32, double-buffered wts/h1s, ONE barrier per chunk.
// Swizzles (derived conflict-free for 8-lane b128 groups):
//   wts/h1s ([r][32] bf16, 64B rows): content-swizzle ks = sl ^ ((r>>1)&3), linear slots.
//   h2s ([r][256] bf16, 512B rows): addr-swizzle slot = ks ^ (r&7).
// ---------------------------------------------------------------------------
__device__ __forceinline__ void stage_w(const unsigned short* __restrict__ W,
                                        unsigned short* dst, int ch, int wid, int lane) {
#pragma unroll
  for (int i = 0; i < 4; ++i) {
    int S = i * 256 + wid * 64 + lane;
    int m = S >> 2, sl = S & 3;
    int ks = sl ^ ((m >> 1) & 3);
    GLDS16(W + m * 256 + ch * 32 + ks * 8, dst + (i * 256 + wid * 64) * 8);
  }
}

__device__ __forceinline__ short8 load_u(const unsigned short* __restrict__ Ub, int ch, int t) {
  int row = t >> 2, sl = t & 3;
  int ks = sl ^ ((row >> 1) & 3);
  return *(const short8*)(Ub + row * 256 + ch * 32 + ks * 8);
}

__device__ __forceinline__ void write_h1(short8 uv, const float* vcs,
                                         unsigned short* dst, int ch, int t) {
  int row = t >> 2, sl = t & 3;
  int ks = sl ^ ((row >> 1) & 3);
  int k0 = ch * 32 + ks * 8;
  f32x4 v0 = *(const f32x4*)(vcs + k0);
  f32x4 v1 = *(const f32x4*)(vcs + k0 + 4);
  float r0 = fmaxf(bf2f((unsigned short)uv[0]) + v0.x, 0.f);
  float r1 = fmaxf(bf2f((unsigned short)uv[1]) + v0.y, 0.f);
  float r2 = fmaxf(bf2f((unsigned short)uv[2]) + v0.z, 0.f);
  float r3 = fmaxf(bf2f((unsigned short)uv[3]) + v0.w, 0.f);
  float r4 = fmaxf(bf2f((unsigned short)uv[4]) + v1.x, 0.f);
  float r5 = fmaxf(bf2f((unsigned short)uv[5]) + v1.y, 0.f);
  float r6 = fmaxf(bf2f((unsigned short)uv[6]) + v1.z, 0.f);
  float r7 = fmaxf(bf2f((unsigned short)uv[7]) + v1.w, 0.f);
  i32x4 wv = { (int)pk2(r0, r1), (int)pk2(r2, r3), (int)pk2(r4, r5), (int)pk2(r6, r7) };
  *(i32x4*)(dst + row * 32 + sl * 8) = wv;
}

__launch_bounds__(256, 2)
__global__ void k_main(const unsigned short* __restrict__ U1, const float* __restrict__ V1,
                       const float* __restrict__ c1,
                       const unsigned short* __restrict__ W2T,
                       const unsigned short* __restrict__ W3T,
                       const float* __restrict__ b2, const float* __restrict__ b3,
                       float* __restrict__ partials) {
  __shared__ unsigned short wts[2][8192];   // 2 x 16KB  [256 feat][32 k]
  __shared__ unsigned short h1s[2][2048];   // 2 x 4KB   [64 row][32 k]
  __shared__ unsigned short h2s[16384];     // 32KB      [64 row][256 c2]
  __shared__ float vcs[256];

  const int t = threadIdx.x;
  const int bid = blockIdx.x;
  const int wrk = ((bid & 7) << 8) + (bid >> 3);   // XCD swizzle (2048 % 8 == 0)
  const int b = wrk >> 6, itile = wrk & 63;
  const int wid = t >> 6, lane = t & 63;
  const int q = lane & 15, g = lane >> 4;
  const int mo = wid << 6;

  vcs[t] = V1[(size_t)(b * 64 + itile) * 256 + t] + c1[t];
  const unsigned short* Ub = U1 + (size_t)(b * 64) * 256;

  // ---- GEMM1 prologue ----
  stage_w(W2T, &wts[0][0], 0, wid, lane);
  short8 u0 = load_u(Ub, 0, t);
  __syncthreads();                       // vcs visible (drains GLDS(0), u0 too)
  write_h1(u0, vcs, &h1s[0][0], 0, t);
  __syncthreads();                       // h1(0) visible

  f32x4 acc[4][4];
#pragma unroll
  for (int mf = 0; mf < 4; ++mf)
#pragma unroll
    for (int nf = 0; nf < 4; ++nf) acc[mf][nf] = (f32x4){0.f, 0.f, 0.f, 0.f};

  // ---- GEMM1: acc = G2^T * h1^T, K=256 in 8 chunks of 32 ----
  for (int ch = 0; ch < 8; ++ch) {
    const unsigned short* wcur = wts[ch & 1];
    const unsigned short* hcur = h1s[ch & 1];
    short8 unext;
    if (ch < 7) {
      stage_w(W2T, (unsigned short*)wts[(ch & 1) ^ 1], ch + 1, wid, lane);
      unext = load_u(Ub, ch + 1, t);
    }
    short8 a_[4], b_[4];
#pragma unroll
    for (int mf = 0; mf < 4; ++mf) {
      int m = mo + 16 * mf + q;
      a_[mf] = *(const short8*)(wcur + m * 32 + ((g ^ ((m >> 1) & 3)) * 8));
    }
#pragma unroll
    for (int nf = 0; nf < 4; ++nf) {
      int r = q + 16 * nf;
      b_[nf] = *(const short8*)(hcur + r * 32 + ((g ^ ((r >> 1) & 3)) * 8));
    }
#pragma unroll
    for (int mf = 0; mf < 4; ++mf)
#pragma unroll
      for (int nf = 0; nf < 4; ++nf)
        acc[mf][nf] = __builtin_amdgcn_mfma_f32_16x16x32_bf16(a_[mf], b_[nf], acc[mf][nf], 0, 0, 0);
    if (ch < 7) write_h1(unext, vcs, (unsigned short*)h1s[(ch & 1) ^ 1], ch + 1, t);
    __syncthreads();
  }

  // ---- h2 = relu(acc + b2) -> h2s; prefetch W3T chunk 0 into wts[0] ----
  stage_w(W3T, &wts[0][0], 0, wid, lane);
#pragma unroll
  for (int mf = 0; mf < 4; ++mf) {
    int c2b = mo + 16 * mf + 4 * g;
    f32x4 bb = *(const f32x4*)(b2 + c2b);
    int ksw = c2b >> 3, off = c2b & 7;
#pragma unroll
    for (int nf = 0; nf < 4; ++nf) {
      int r = q + 16 * nf;
      f32x4 v = acc[mf][nf];
      float e0 = fmaxf(v.x + bb.x, 0.f), e1 = fmaxf(v.y + bb.y, 0.f);
      float e2 = fmaxf(v.z + bb.z, 0.f), e3 = fmaxf(v.w + bb.w, 0.f);
      i32x2 wv = { (int)pk2(e0, e1), (int)pk2(e2, e3) };
      *(i32x2*)(h2s + r * 256 + ((ksw ^ (r & 7)) * 8) + off) = wv;
    }
  }
  __syncthreads();                       // h2s + W3T(0) visible

  f32x4 acc2[4][4];
#pragma unroll
  for (int mf = 0; mf < 4; ++mf)
#pragma unroll
    for (int nf = 0; nf < 4; ++nf) acc2[mf][nf] = (f32x4){0.f, 0.f, 0.f, 0.f};

  // ---- GEMM2: acc2 = G3^T * h2^T, K=256 in 8 chunks of 32 ----
  for (int ch = 0; ch < 8; ++ch) {
    const unsigned short* wcur = wts[ch & 1];
    if (ch < 7)
      stage_w(W3T, (unsigned short*)wts[(ch & 1) ^ 1], ch + 1, wid, lane);
    short8 a_[4], b_[4];
#pragma unroll
    for (int mf = 0; mf < 4; ++mf) {
      int m = mo + 16 * mf + q;
      a_[mf] = *(const short8*)(wcur + m * 32 + ((g ^ ((m >> 1) & 3)) * 8));
    }
#pragma unroll
    for (int nf = 0; nf < 4; ++nf) {
      int r = q + 16 * nf;
      int ks = ch * 4 + g;
      b_[nf] = *(const short8*)(h2s + r * 256 + ((ks ^ (r & 7)) * 8));
    }
#pragma unroll
    for (int mf = 0; mf < 4; ++mf)
#pragma unroll
      for (int nf = 0; nf < 4; ++nf)
        acc2[mf][nf] = __builtin_amdgcn_mfma_f32_16x16x32_bf16(a_[mf], b_[nf], acc2[mf][nf], 0, 0, 0);
    __syncthreads();
  }

  // ---- h3 = relu(acc2 + b3); row-sum (in-frag + q-butterfly); direct store ----
#pragma unroll
  for (int mf = 0; mf < 4; ++mf) {
    int n3b = mo + 16 * mf + 4 * g;
    f32x4 bb = *(const f32x4*)(b3 + n3b);
    f32x4 sum = (f32x4){0.f, 0.f, 0.f, 0.f};
#pragma unroll
    for (int nf = 0; nf < 4; ++nf) {
      f32x4 v = acc2[mf][nf];
      sum.x += fmaxf(v.x + bb.x, 0.f);
      sum.y += fmaxf(v.y + bb.y, 0.f);
      sum.z += fmaxf(v.z + bb.z, 0.f);
      sum.w += fmaxf(v.w + bb.w, 0.f);
    }
#pragma unroll
    for (int msk = 1; msk < 16; msk <<= 1) {
      sum.x += __shfl_xor(sum.x, msk);
      sum.y += __shfl_xor(sum.y, msk);
      sum.z += __shfl_xor(sum.z, msk);
      sum.w += __shfl_xor(sum.w, msk);
    }
    if (q == 0) *(f32x4*)(partials + (size_t)wrk * 256 + n3b) = sum;
  }
}

// ---------------------------------------------------------------------------
// Reduce partials per batch + f-MLP (f32). grid 32 x 256. (unchanged)
// ---------------------------------------------------------------------------
__global__ void k_fmlp(const float* __restrict__ partials,
                       const float* __restrict__ f1w, const float* __restrict__ f1b,
                       const float* __restrict__ f2w, const float* __restrict__ f2b,
                       const float* __restrict__ f3w, const float* __restrict__ f3b,
                       float* __restrict__ out) {
  const int b = blockIdx.x, t = threadIdx.x;
  __shared__ float xg[256], x1[256], x2[256];
  float s = 0.f;
  for (int k = 0; k < 64; ++k) s += partials[(size_t)(b * 64 + k) * 256 + t];
  xg[t] = s;
  __syncthreads();
  float a1 = f1b[t];
  for (int k = 0; k < 256; ++k) a1 += xg[k] * f1w[k * 256 + t];
  x1[t] = fmaxf(a1, 0.f);
  __syncthreads();
  float a2 = f2b[t];
  for (int k = 0; k < 256; ++k) a2 += x1[k] * f2w[k * 256 + t];
  x2[t] = fmaxf(a2, 0.f);
  __syncthreads();
  if (t < 128) {
    float a3 = f3b[t];
    for (int k = 0; k < 256; ++k) a3 += x2[k] * f3w[k * 128 + t];
    out[b * 128 + t] = a3;
  }
}

__global__ void k_zero(float* __restrict__ out, int n) {
  int i = blockIdx.x * 256 + threadIdx.x;
  if (i < n) out[i] = 0.f;
}

// ---------------------------------------------------------------------------
extern "C" void kernel_launch(void* const* d_in, const int* in_sizes, int n_in,
                              void* d_out, int out_size, void* d_ws, size_t ws_size,
                              hipStream_t stream) {
  const float* x      = (const float*)d_in[0];
  const float* edge_w = (const float*)d_in[1];
  const float* edge_b = (const float*)d_in[2];
  const float *gw0, *gw1, *gw2, *gb0, *gb1, *gb2;
  const float *f1w, *f1b, *f2w, *f2b, *f3w, *f3b;

  if (n_in >= 15 && in_sizes[3] == 65536 && in_sizes[4] == 65536 && in_sizes[5] == 65536) {
    gw0 = (const float*)d_in[3]; gw1 = (const float*)d_in[4]; gw2 = (const float*)d_in[5];
    gb0 = (const float*)d_in[6]; gb1 = (const float*)d_in[7]; gb2 = (const float*)d_in[8];
    f1w = (const float*)d_in[9];  f1b = (const float*)d_in[10];
    f2w = (const float*)d_in[11]; f2b = (const float*)d_in[12];
    f3w = (const float*)d_in[13]; f3b = (const float*)d_in[14];
  } else if (n_in >= 15 && in_sizes[3] == 65536 && in_sizes[4] == 256) {
    gw0 = (const float*)d_in[3]; gb0 = (const float*)d_in[4];
    gw1 = (const float*)d_in[5]; gb1 = (const float*)d_in[6];
    gw2 = (const float*)d_in[7]; gb2 = (const float*)d_in[8];
    f1w = (const float*)d_in[9];  f1b = (const float*)d_in[10];
    f2w = (const float*)d_in[11]; f2b = (const float*)d_in[12];
    f3w = (const float*)d_in[13]; f3b = (const float*)d_in[14];
  } else {
    const float* gws = (const float*)d_in[3];
    const float* gbs = (const float*)d_in[4];
    gw0 = gws;          gw1 = gws + 65536;  gw2 = gws + 131072;
    gb0 = gbs;          gb1 = gbs + 256;    gb2 = gbs + 512;
    f1w = (const float*)d_in[5];  f1b = (const float*)d_in[6];
    f2w = (const float*)d_in[7];  f2b = (const float*)d_in[8];
    f3w = (const float*)d_in[9];  f3b = (const float*)d_in[10];
  }

  char* ws = (char*)d_ws;
  float*          W1u      = (float*)(ws);                    // 256KB
  float*          W1v      = (float*)(ws + 262144);           // 256KB
  float*          c1       = (float*)(ws + 524288);           // 1KB
  unsigned short* W2T      = (unsigned short*)(ws + 525312);  // 128KB
  unsigned short* W3T      = (unsigned short*)(ws + 656384);  // 128KB
  unsigned short* U1       = (unsigned short*)(ws + 787456);  // 1MB   (bf16)
  float*          V1       = (float*)(ws + 1836032);          // 2MB
  float*          partials = (float*)(ws + 3933184);          // 2MB
  const size_t need = 6030336;
  (void)out_size; (void)n_in;

  if (ws_size < need) {
    k_zero<<<dim3((out_size + 255) / 256), dim3(256), 0, stream>>>((float*)d_out, out_size);
    return;
  }

  k_prep<<<dim3(513), dim3(256), 0, stream>>>(edge_w, edge_b, gw0, gb0, gw1, gw2,
                                              W1u, W1v, c1, W2T, W3T);
  k_uv<<<dim3(256), dim3(512), 0, stream>>>(x, W1u, W1v, U1, V1);
  k_main<<<dim3(2048), dim3(256), 0, stream>>>(U1, V1, c1, W2T, W3T, gb1, gb2, partials);
  k_fmlp<<<dim3(32), dim3(256), 0, stream>>>(partials, f1w, f1b, f2w, f2b, f3w, f3b,
                                             (float*)d_out);
}